// Round 8
// baseline (700.733 us; speedup 1.0000x reference)
//
#include <hip/hip_runtime.h>

typedef __attribute__((ext_vector_type(4))) float f32x4;
typedef unsigned char u8;
typedef unsigned long long u64t;

#define BIG_NEG -1000000000.0f

static constexpr int B_  = 256;
static constexpr int SX_ = 34;
static constexpr int SY_ = 34;
static constexpr int IND = 66;   // IN_DIM
static constexpr int OP_ = 80;   // padded OUT_DIM (65 -> 80)

__device__ __forceinline__ f32x4 mfma_fp8(long a, long b, f32x4 c) {
  return __builtin_amdgcn_mfma_f32_16x16x32_fp8_fp8(a, b, c, 0, 0, 0);
}
__device__ __forceinline__ float sigm(float x)  { return 1.0f / (1.0f + __expf(-x)); }
__device__ __forceinline__ float tanhx(float x) { return 2.0f * sigm(2.0f * x) - 1.0f; }
template <bool HI>
__device__ __forceinline__ unsigned pk2(float a, float b, unsigned old) {
  return __builtin_amdgcn_cvt_pk_fp8_f32(a, b, (int)old, HI);
}

// ---------------------------------------------------------------------------
// prep kernels
// ---------------------------------------------------------------------------
__global__ void decode_tokens(const float* __restrict__ src,
                              const float* __restrict__ tgt,
                              int* __restrict__ tok_x, int* __restrict__ tok_y) {
  int idx = blockIdx.x * 256 + threadIdx.x;
  const int half = SX_ * B_;
  if (idx >= 2 * half) return;
  const float* base = (idx < half) ? src : tgt;
  int* outp         = (idx < half) ? tok_x : tok_y;
  int k = (idx < half) ? idx : idx - half;
  const float* p = base + (size_t)k * IND;
  int tok = -1;
  for (int v = 0; v < IND; ++v) if (p[v] > 0.5f) tok = v;
  outp[k] = tok;
}

// all three Whh -> fp8, one launch (grid-stride over 4B words = 4 floats)
__global__ void conv_fp8_all(const float* __restrict__ Wf, const float* __restrict__ Wr,
                             const float* __restrict__ Wm,
                             u8* __restrict__ of, u8* __restrict__ orr, u8* __restrict__ om) {
  const int F4 = 2048 * 512 / 4;
  const int M4 = 4096 * 1024 / 4;
  int i = blockIdx.x * 256 + threadIdx.x;
  int stride = gridDim.x * 256;
  for (; i < 2 * F4 + M4; i += stride) {
    const float* src; unsigned* dst; int k;
    if (i < F4)          { src = Wf; dst = (unsigned*)of;  k = i; }
    else if (i < 2 * F4) { src = Wr; dst = (unsigned*)orr; k = i - F4; }
    else                 { src = Wm; dst = (unsigned*)om;  k = i - 2 * F4; }
    float4 f = ((const float4*)src)[k];
    unsigned w = pk2<false>(f.x, f.y, 0);
    w = pk2<true>(f.z, f.w, w);
    dst[k] = w;
  }
}

// E[v][n] = (v<66 ? Wih[n][v] : 0) + bias[n]  — LDS-tiled transpose, all 3 models.
__global__ __launch_bounds__(256) void build_E_all(
    const float* __restrict__ Wf, const float* __restrict__ bf,
    const float* __restrict__ Wr, const float* __restrict__ br,
    const float* __restrict__ Wm, const float* __restrict__ bm,
    float* __restrict__ Ef, float* __restrict__ Er, float* __restrict__ Em) {
  __shared__ float tile[64 * 67];
  int tb = blockIdx.x;
  const float* W; const float* bias; float* E; int H4; int n0;
  if (tb < 32)      { W = Wf; bias = bf; E = Ef; H4 = 2048; n0 = tb * 64; }
  else if (tb < 64) { W = Wr; bias = br; E = Er; H4 = 2048; n0 = (tb - 32) * 64; }
  else              { W = Wm; bias = bm; E = Em; H4 = 4096; n0 = (tb - 64) * 64; }
  const float* src = W + (size_t)n0 * IND;
  for (int i = threadIdx.x; i < 64 * IND; i += 256) {
    int n = i / IND, v = i - n * IND;
    tile[n * 67 + v] = src[i];
  }
  __syncthreads();
  int lane = threadIdx.x & 63, w = threadIdx.x >> 6;
  float bl = bias[n0 + lane];
  for (int v = w; v < 67; v += 4) {
    float val = (v < 66 ? tile[lane * 67 + v] : 0.f) + bl;
    E[(size_t)v * H4 + n0 + lane] = val;
  }
}

// Wcat: fp8 [160][1024]; rows 0..79 = W_sub (padded), 80..159 = W_ins
__global__ void pad_head_w(const float* __restrict__ Wsub, const float* __restrict__ Wins,
                           u8* __restrict__ Wcat) {
  int widx = blockIdx.x * 256 + threadIdx.x;  // one 4-byte word
  if (widx >= 160 * 256) return;
  int row = widx >> 8;
  int wc  = widx & 255;
  int srow = row < 80 ? row : row - 80;
  const float* W = row < 80 ? Wsub : Wins;
  float f0 = 0.f, f1 = 0.f, f2 = 0.f, f3 = 0.f;
  if (srow < 65) {
    const float* p = W + (size_t)srow * 1024 + wc * 4;
    f0 = p[0]; f1 = p[1]; f2 = p[2]; f3 = p[3];
  }
  unsigned w = pk2<false>(f0, f1, 0);
  w = pk2<true>(f2, f3, w);
  ((unsigned*)Wcat)[widx] = w;
}

// ---------------------------------------------------------------------------
// persistent LSTM: 256 blocks x 256 thr (1/CU), XCD-swizzled domains.
//   blockIdx = xcd + 8*slot: slot<16 -> mod(c=xcd, s=slot)
//                            slot<24 -> fwd(c=xcd, s=slot-16)
//                            else   -> rev(c=xcd, s=slot-24)
// Each barrier domain (one batch chunk of one role) sits on one XCD
// (heuristic only). h: agent store (LLC, correctness) + plain store
// (L2-dirty, same-XCD fast path); consumers use plain loads.
// Flags stay agent-scope; each thread polls only its own producer's flag.
// ---------------------------------------------------------------------------
template <int HH>
__device__ __forceinline__ void run_lstm(
    const u8* __restrict__ w8, const float* __restrict__ E,
    bool revr, u8* __restrict__ hall, int b0, int h0,
    unsigned* __restrict__ flags, int dom0, int myid,
    u8* __restrict__ alds, u8* __restrict__ hT, const u8* __restrict__ tok_small) {
  const int tid = threadIdx.x;
  const int lane = tid & 63, w = tid >> 6;
  const int lo = lane & 15, q = lane >> 4;
  constexpr int AST = HH + 8;          // padded LDS row stride (bytes)
  constexpr int U8C = HH / 8;
  constexpr int USH = (HH == 1024) ? 7 : 6;
  constexpr int NI  = (32 * U8C) / 256;   // 8 (fwd/rev) or 16 (mod)
  constexpr int NK  = HH / 32;
  const int hu = h0 + w * 16 + lo;     // this lane's h-unit
  const int myp = (tid & (U8C - 1)) >> 3;  // producer slice this thread reads

  const u8* brow[4];
  long breg[4][16];                    // resident K (first 512) weights
#pragma unroll
  for (int g = 0; g < 4; ++g) {
    brow[g] = w8 + (size_t)(g * HH + hu) * HH + q * 8;
#pragma unroll
    for (int kk = 0; kk < 16; ++kk)
      breg[g][kk] = *(const long*)(brow[g] + kk * 32);
  }
  float creg[8] = {0.f, 0.f, 0.f, 0.f, 0.f, 0.f, 0.f, 0.f};

  for (int t = 0; t < 34; ++t) {
    // ---- poll own producer's flag (agent), then plain-load A-tile ----
    if (t > 0) {
      const unsigned tgt = (unsigned)t;
      int spin = 0;
      while (__hip_atomic_load(&flags[(dom0 + myp) * 32], __ATOMIC_RELAXED,
                               __HIP_MEMORY_SCOPE_AGENT) < tgt) {
        __builtin_amdgcn_s_sleep(1);
        if (++spin > (1 << 17)) break;   // safety exit
      }
      __asm__ volatile("" ::: "memory"); // no hoisting loads above the poll
    }
    const u8* hsrc = hall + (size_t)t * (256 * HH);
    u64t tmp[NI];
#pragma unroll
    for (int ii = 0; ii < NI; ++ii) {
      int idx = tid + ii * 256;
      tmp[ii] = *(const u64t*)(hsrc + (size_t)(b0 + (idx >> USH)) * HH +
                               (idx & (U8C - 1)) * 8);
    }
#pragma unroll
    for (int ii = 0; ii < NI; ++ii) {
      int idx = tid + ii * 256;
      *(u64t*)&alds[(idx >> USH) * AST + (idx & (U8C - 1)) * 8] = tmp[ii];
    }
    __syncthreads();

    f32x4 acc[2][4];
#pragma unroll
    for (int mt = 0; mt < 2; ++mt)
#pragma unroll
      for (int g = 0; g < 4; ++g) acc[mt][g] = (f32x4){0.f, 0.f, 0.f, 0.f};

    const u8* a0p = alds + lo * AST + q * 8;
    const u8* a1p = alds + (16 + lo) * AST + q * 8;
#pragma unroll
    for (int kk = 0; kk < 16; ++kk) {
      long a0 = *(const long*)(a0p + kk * 32);
      long a1 = *(const long*)(a1p + kk * 32);
#pragma unroll
      for (int g = 0; g < 4; ++g) {
        acc[0][g] = mfma_fp8(a0, breg[g][kk], acc[0][g]);
        acc[1][g] = mfma_fp8(a1, breg[g][kk], acc[1][g]);
      }
    }
    if (HH == 1024) {                  // streamed upper-K (same-XCD L2)
#pragma unroll
      for (int kk = 16; kk < NK; ++kk) {
        long bg[4];
#pragma unroll
        for (int g = 0; g < 4; ++g) bg[g] = *(const long*)(brow[g] + kk * 32);
        long a0 = *(const long*)(a0p + kk * 32);
        long a1 = *(const long*)(a1p + kk * 32);
#pragma unroll
        for (int g = 0; g < 4; ++g) {
          acc[0][g] = mfma_fp8(a0, bg[g], acc[0][g]);
          acc[1][g] = mfma_fp8(a1, bg[g], acc[1][g]);
        }
      }
    }

    // ---- epilogue: E-gather + gate math; pack fp8 into hT (LDS) ----
    int tpos = revr ? 33 - t : t;
    const u8* tkp = tok_small + tpos * 32;
#pragma unroll
    for (int mt = 0; mt < 2; ++mt) {
      float hv[4];
#pragma unroll
      for (int r = 0; r < 4; ++r) {
        int m = mt * 16 + q * 4 + r;
        int v = tkp[m];
        const float* e = E + (size_t)v * (4 * HH) + hu;
        float g4[4];
#pragma unroll
        for (int g = 0; g < 4; ++g) g4[g] = acc[mt][g][r] + e[g * HH];
        float cold = creg[mt * 4 + r];
        float cn = sigm(g4[1]) * cold + sigm(g4[0]) * tanhx(g4[2]);
        hv[r] = sigm(g4[3]) * tanhx(cn);
        creg[mt * 4 + r] = cn;
      }
      unsigned pw = pk2<false>(hv[0], hv[1], 0);
      pw = pk2<true>(hv[2], hv[3], pw);
      *(unsigned*)&hT[(w * 16 + lo) * 36 + mt * 16 + q * 4] = pw;
    }
    __syncthreads();

    // ---- coalesced 8B store: agent (LLC, correctness) + plain (L2 fast) ----
    {
      int m = tid >> 3, cc = tid & 7;
      u64t val = 0;
#pragma unroll
      for (int k = 0; k < 8; ++k)
        val |= (u64t)hT[(cc * 8 + k) * 36 + m] << (8 * k);
      u8* hdst = hall + (size_t)(t + 1) * (256 * HH);
      u64t* p = (u64t*)(hdst + (size_t)(b0 + m) * HH + h0 + cc * 8);
      __hip_atomic_store(p, val, __ATOMIC_RELAXED, __HIP_MEMORY_SCOPE_AGENT);
      *p = val;                        // same data; dirty line in local L2
    }

    // ---- drain own stores, post flag ----
    if (t < 33) {
      __asm__ volatile("s_waitcnt vmcnt(0)" ::: "memory");
      __syncthreads();
      if (tid == 0)
        __hip_atomic_store(&flags[(dom0 + myid) * 32], (unsigned)(t + 1),
                           __ATOMIC_RELAXED, __HIP_MEMORY_SCOPE_AGENT);
    }
  }
}

__global__ __launch_bounds__(256, 1) void lstm_persist(
    const int* __restrict__ tok_x, const int* __restrict__ tok_y,
    const float* __restrict__ E_f, const u8* __restrict__ w8_f,
    const float* __restrict__ E_r, const u8* __restrict__ w8_r,
    const float* __restrict__ E_m, const u8* __restrict__ w8_m,
    u8* __restrict__ fwd_all, u8* __restrict__ rev_all, u8* __restrict__ y_all,
    unsigned* __restrict__ flags) {
  __shared__ u8 alds[32 * 1032];       // 33 KB A-stage (fwd/rev use 32*520)
  __shared__ u8 hT[64 * 36];           // store-transpose buffer
  __shared__ u8 tok_small[34 * 32];    // this block's tokens (66 = none)

  const int b = blockIdx.x;
  const int xcd = b & 7, slot = b >> 3;
  int role, c, s;
  if (slot < 16)      { role = 2; c = xcd; s = slot; }        // mod: 128 blks
  else if (slot < 24) { role = 0; c = xcd; s = slot - 16; }   // fwd: 64
  else                { role = 1; c = xcd; s = slot - 24; }   // rev: 64

  const float* E  = role == 0 ? E_f  : role == 1 ? E_r  : E_m;
  const u8*    w8 = role == 0 ? w8_f : role == 1 ? w8_r : w8_m;
  u8* hall        = role == 0 ? fwd_all : role == 1 ? rev_all : y_all;
  const int* tokg = (role == 2) ? tok_y : tok_x;
  const int b0 = c * 32;
  const int h0 = s * 64;
  const int dom0 = (role == 2) ? c * 16 : (role == 0) ? 128 + c * 8 : 192 + c * 8;

  for (int i = threadIdx.x; i < 34 * 32; i += 256) {
    int t2 = i >> 5, m = i & 31;
    int tk = tokg[t2 * 256 + b0 + m];
    tok_small[i] = (u8)(tk < 0 ? 66 : tk);
  }
  __syncthreads();

  if (role == 2)
    run_lstm<1024>(w8, E, false, hall, b0, h0, flags, dom0, s, alds, hT, tok_small);
  else
    run_lstm<512>(w8, E, role == 1, hall, b0, h0, flags, dom0, s, alds, hT, tok_small);
}

// ---------------------------------------------------------------------------
// head: lx = x_emb @ W^T, ly = y_emb @ W^T + b, both heads (W rows 0..159).
// 136 blocks x 256 thr; A-loads issued BEFORE W staging (latency overlap).
// ---------------------------------------------------------------------------
__global__ __launch_bounds__(256, 1) void head_kernel(
    const u8* __restrict__ fwd_all, const u8* __restrict__ rev_all,
    const u8* __restrict__ y_all, const u8* __restrict__ Wcat,
    const float* __restrict__ b_sub, const float* __restrict__ b_ins,
    float* __restrict__ lx_sub, float* __restrict__ lx_ins,
    float* __restrict__ ly_sub, float* __restrict__ ly_ins) {
  __shared__ u8 wq[160 * 264];   // 42240 B, row pad 264 for bank spread
  const int lane = threadIdx.x & 63, wave = threadIdx.x >> 6;
  const int lo = lane & 15, q = lane >> 4;
  int blk = blockIdx.x;
  bool yside = (blk >= 68);
  int mb = yside ? blk - 68 : blk;
  int ij = mb >> 1;
  int bbase = (mb & 1) * 128;

  f32x4 acc[2][10];
#pragma unroll
  for (int mt = 0; mt < 2; ++mt)
#pragma unroll
    for (int nn = 0; nn < 10; ++nn) acc[mt][nn] = (f32x4){0.f,0.f,0.f,0.f};

  for (int qk = 0; qk < 4; ++qk) {
    // A-fragment loads first (independent of LDS) -> overlap with staging
    long aA[2][8];
#pragma unroll
    for (int mt = 0; mt < 2; ++mt) {
      int row = bbase + wave * 32 + mt * 16 + lo;
      const u8* ab;
      if (yside)
        ab = y_all + ((size_t)(ij + 1) * 256 + row) * 1024 + qk * 256 + q * 8;
      else if (qk < 2)
        ab = fwd_all + ((size_t)(ij + 1) * 256 + row) * 512 + qk * 256 + q * 8;
      else
        ab = rev_all + ((size_t)(34 - ij) * 256 + row) * 512 + (qk - 2) * 256 + q * 8;
#pragma unroll
      for (int ki = 0; ki < 8; ++ki) aA[mt][ki] = *(const long*)(ab + ki * 32);
    }

    for (int c8 = threadIdx.x; c8 < 160 * 32; c8 += 256) {
      int row = c8 >> 5, col = (c8 & 31) << 3;
      *(long*)&wq[row * 264 + col] =
          *(const long*)&Wcat[(size_t)row * 1024 + qk * 256 + col];
    }
    __syncthreads();

#pragma unroll
    for (int ki = 0; ki < 8; ++ki) {
#pragma unroll
      for (int nn = 0; nn < 10; ++nn) {
        long bf = *(const long*)&wq[(nn * 16 + lo) * 264 + ki * 32 + q * 8];
        acc[0][nn] = mfma_fp8(aA[0][ki], bf, acc[0][nn]);
        acc[1][nn] = mfma_fp8(aA[1][ki], bf, acc[1][nn]);
      }
    }
    __syncthreads();
  }

#pragma unroll
  for (int mt = 0; mt < 2; ++mt) {
#pragma unroll
    for (int nn = 0; nn < 10; ++nn) {
      bool is_sub = (nn < 5);
      int n = (is_sub ? nn : nn - 5) * 16 + lo;
      float bias = 0.0f;
      if (yside && n < 65) bias = is_sub ? b_sub[n] : b_ins[n];
      float* dst = yside ? (is_sub ? ly_sub : ly_ins) : (is_sub ? lx_sub : lx_ins);
#pragma unroll
      for (int r = 0; r < 4; ++r) {
        int b = bbase + wave * 32 + mt * 16 + q * 4 + r;
        dst[((size_t)ij * 256 + b) * OP_ + n] = acc[mt][nn][r] + bias;
      }
    }
  }
}

// ---------------------------------------------------------------------------
// pair: per (i,j,b) logsumexp over 65 of lx+ly for both heads.
// 136 blocks (34 i x 4 b-chunks) x 256 thr (64 b x 4 j-lanes); lx in regs.
// ---------------------------------------------------------------------------
__device__ __forceinline__ void lse_regs(const float4* __restrict__ X,
                                         const float* __restrict__ py, int sym,
                                         float& logZ, float& v64, float& vs) {
  const float4* py4 = (const float4*)py;
  float4 Y[17];
#pragma unroll
  for (int q = 0; q < 17; ++q) Y[q] = py4[q];
  float mm = -3.4e38f;
#pragma unroll
  for (int q = 0; q < 17; ++q) {
    float vx[4] = {X[q].x + Y[q].x, X[q].y + Y[q].y, X[q].z + Y[q].z, X[q].w + Y[q].w};
#pragma unroll
    for (int c = 0; c < 4; ++c) {
      int o = q * 4 + c;
      if (o < 65) mm = fmaxf(mm, vx[c]);
    }
  }
  float ss = 0.f, vsl = 0.f, vend = 0.f;
#pragma unroll
  for (int q = 0; q < 17; ++q) {
    float vx[4] = {X[q].x + Y[q].x, X[q].y + Y[q].y, X[q].z + Y[q].z, X[q].w + Y[q].w};
#pragma unroll
    for (int c = 0; c < 4; ++c) {
      int o = q * 4 + c;
      if (o < 65) {
        ss += __expf(vx[c] - mm);
        if (o == 64) vend = vx[c];
        if (o == sym) vsl = vx[c];
      }
    }
  }
  logZ = mm + __logf(ss);
  v64 = vend;
  vs = vsl;
}

__global__ __launch_bounds__(256, 1) void pair_kernel(
    const int* __restrict__ tok_x, const int* __restrict__ tok_y,
    const float* __restrict__ lx_sub, const float* __restrict__ lx_ins,
    const float* __restrict__ ly_sub, const float* __restrict__ ly_ins,
    float* __restrict__ out) {
  const int i = blockIdx.x >> 2;
  const int bc = blockIdx.x & 3;
  const int jq = threadIdx.x >> 6;
  const int bl = threadIdx.x & 63;
  const int b = bc * 64 + bl;
  const size_t CH = (size_t)SX_ * SY_ * B_;

  float4 Xs[17], Xi[17];
  {
    const float4* ps = (const float4*)(lx_sub + ((size_t)i * 256 + b) * OP_);
    const float4* pi = (const float4*)(lx_ins + ((size_t)i * 256 + b) * OP_);
#pragma unroll
    for (int q = 0; q < 17; ++q) { Xs[q] = ps[q]; Xi[q] = pi[q]; }
  }
  int tx = tok_x[i * 256 + b];

  for (int j = jq; j < 34; j += 4) {
    size_t obase = ((size_t)i * SY_ + j) * 256 + b;
    bool dead = (j == SY_ - 1) || (tx < 0);
    if (!dead) {
      int ty = tok_y[j * 256 + b];
      if (ty < 0) dead = true;
    }
    if (dead) {
      out[obase] = BIG_NEG;
      out[CH + obase] = BIG_NEG;
      out[2 * CH + obase] = BIG_NEG;
      out[3 * CH + obase] = BIG_NEG;
      continue;
    }
    int tn = tok_y[(j + 1) * 256 + b];
    bool ins_ok = (tn != 65);
    int sym = (tn >= 0 && tn < 64) ? tn : -1;

    float logZs, v64s, vss;
    lse_regs(Xs, ly_sub + ((size_t)j * 256 + b) * OP_, sym, logZs, v64s, vss);
    float dlt = v64s - logZs;
    float sub_val = (sym >= 0) ? (vss - logZs) : 0.0f;

    float logZi, v64i, vsi;
    lse_regs(Xi, ly_ins + ((size_t)j * 256 + b) * OP_, sym, logZi, v64i, vsi);
    float endv = v64i - logZi;
    float ins_val = (sym >= 0) ? (vsi - logZi) : 0.0f;

    out[obase]          = ins_ok ? ins_val : BIG_NEG;
    out[CH + obase]     = ins_ok ? sub_val : BIG_NEG;
    out[2 * CH + obase] = endv;
    out[3 * CH + obase] = dlt;
  }
}

// ---------------------------------------------------------------------------
// launch
// ---------------------------------------------------------------------------
extern "C" void kernel_launch(void* const* d_in, const int* in_sizes, int n_in,
                              void* d_out, int out_size, void* d_ws, size_t ws_size,
                              hipStream_t stream) {
  const float* sources = (const float*)d_in[0];
  const float* targets = (const float*)d_in[1];
  const float* Wih_f = (const float*)d_in[2];
  const float* Whh_f = (const float*)d_in[3];
  const float* b_f   = (const float*)d_in[4];
  const float* Wih_r = (const float*)d_in[5];
  const float* Whh_r = (const float*)d_in[6];
  const float* b_r   = (const float*)d_in[7];
  const float* Wih_m = (const float*)d_in[8];
  const float* Whh_m = (const float*)d_in[9];
  const float* b_m   = (const float*)d_in[10];
  const float* W_sub = (const float*)d_in[11];
  const float* b_sub = (const float*)d_in[12];
  const float* W_ins = (const float*)d_in[13];
  const float* b_ins = (const float*)d_in[14];
  float* out = (float*)d_out;

  char* w = (char*)d_ws;
  constexpr size_t FLAG_SZ = 256 * 32 * 4;                  // 32 KB, 128B-spread
  constexpr size_t TOK_SZ  = (size_t)SX_ * B_ * 4;
  constexpr size_t WCAT_SZ = (size_t)160 * 1024;            // head W fp8
  constexpr size_t W8F_SZ  = (size_t)2048 * 512;            // fwd Whh fp8
  constexpr size_t W8M_SZ  = (size_t)4096 * 1024;           // mod Whh fp8
  constexpr size_t EF_SZ   = (size_t)67 * 2048 * 4;         // E tables f32
  constexpr size_t EM_SZ   = (size_t)67 * 4096 * 4;
  constexpr size_t LX_SZ   = (size_t)SX_ * B_ * OP_ * 4;
  constexpr size_t HF_SZ   = (size_t)35 * B_ * 512;         // h slabs fp8
  constexpr size_t HM_SZ   = (size_t)35 * B_ * 1024;

  size_t off = 0;
  unsigned* flags = (unsigned*)(w + off); off += FLAG_SZ;
  int*  tok_x   = (int*)(w + off);  off += TOK_SZ;
  int*  tok_y   = (int*)(w + off);  off += TOK_SZ;
  off = (off + 255) & ~(size_t)255;
  u8*   Wcat    = (u8*)(w + off);   off += WCAT_SZ;
  u8*   w8_f    = (u8*)(w + off);   off += W8F_SZ;
  u8*   w8_r    = (u8*)(w + off);   off += W8F_SZ;
  u8*   w8_m    = (u8*)(w + off);   off += W8M_SZ;
  float* E_f    = (float*)(w + off); off += EF_SZ;
  float* E_r    = (float*)(w + off); off += EF_SZ;
  float* E_m    = (float*)(w + off); off += EM_SZ;
  float* lx_sub = (float*)(w + off); off += LX_SZ;
  float* lx_ins = (float*)(w + off); off += LX_SZ;
  float* ly_sub = (float*)(w + off); off += LX_SZ;
  float* ly_ins = (float*)(w + off); off += LX_SZ;
  u8* fwd_all   = (u8*)(w + off);   off += HF_SZ;
  u8* rev_all   = (u8*)(w + off);   off += HF_SZ;
  u8* y_all     = (u8*)(w + off);   off += HM_SZ;
  (void)ws_size; (void)in_sizes; (void)n_in; (void)out_size;

  // zero: flags + t=0 h slabs
  (void)hipMemsetAsync(flags, 0, FLAG_SZ, stream);
  (void)hipMemsetAsync(fwd_all, 0, (size_t)B_ * 512, stream);
  (void)hipMemsetAsync(rev_all, 0, (size_t)B_ * 512, stream);
  (void)hipMemsetAsync(y_all,   0, (size_t)B_ * 1024, stream);

  decode_tokens<<<(2 * SX_ * B_ + 255) / 256, 256, 0, stream>>>(sources, targets, tok_x, tok_y);
  pad_head_w<<<160, 256, 0, stream>>>(W_sub, W_ins, Wcat);
  conv_fp8_all<<<3072, 256, 0, stream>>>(Whh_f, Whh_r, Whh_m, w8_f, w8_r, w8_m);
  build_E_all<<<128, 256, 0, stream>>>(Wih_f, b_f, Wih_r, b_r, Wih_m, b_m, E_f, E_r, E_m);

  lstm_persist<<<256, 256, 0, stream>>>(
      tok_x, tok_y,
      E_f, w8_f,
      E_r, w8_r,
      E_m, w8_m,
      fwd_all, rev_all, y_all, flags);

  head_kernel<<<136, 256, 0, stream>>>(fwd_all, rev_all, y_all, Wcat,
                                       b_sub, b_ins, lx_sub, lx_ins, ly_sub, ly_ins);

  pair_kernel<<<136, 256, 0, stream>>>(tok_x, tok_y, lx_sub, lx_ins,
                                       ly_sub, ly_ins, out);
}

// Round 9
// 370.553 us; speedup vs baseline: 1.8910x; 1.8910x over previous
//
#include <hip/hip_runtime.h>

typedef __attribute__((ext_vector_type(4))) float f32x4;
typedef unsigned char u8;
typedef unsigned long long u64t;

#define BIG_NEG -1000000000.0f

static constexpr int B_  = 256;
static constexpr int SX_ = 34;
static constexpr int SY_ = 34;
static constexpr int IND = 66;   // IN_DIM
static constexpr int OP_ = 80;   // padded OUT_DIM (65 -> 80)

__device__ __forceinline__ f32x4 mfma_fp8(long a, long b, f32x4 c) {
  return __builtin_amdgcn_mfma_f32_16x16x32_fp8_fp8(a, b, c, 0, 0, 0);
}
__device__ __forceinline__ float sigm(float x)  { return 1.0f / (1.0f + __expf(-x)); }
__device__ __forceinline__ float tanhx(float x) { return 2.0f * sigm(2.0f * x) - 1.0f; }
template <bool HI>
__device__ __forceinline__ unsigned pk2(float a, float b, unsigned old) {
  return __builtin_amdgcn_cvt_pk_fp8_f32(a, b, (int)old, HI);
}

// ---------------------------------------------------------------------------
// prep kernels
// ---------------------------------------------------------------------------
__global__ void decode_tokens(const float* __restrict__ src,
                              const float* __restrict__ tgt,
                              int* __restrict__ tok_x, int* __restrict__ tok_y) {
  int idx = blockIdx.x * 256 + threadIdx.x;
  const int half = SX_ * B_;
  if (idx >= 2 * half) return;
  const float* base = (idx < half) ? src : tgt;
  int* outp         = (idx < half) ? tok_x : tok_y;
  int k = (idx < half) ? idx : idx - half;
  const float* p = base + (size_t)k * IND;
  int tok = -1;
  for (int v = 0; v < IND; ++v) if (p[v] > 0.5f) tok = v;
  outp[k] = tok;
}

// all three Whh -> fp8, one launch (grid-stride over 4B words = 4 floats)
__global__ void conv_fp8_all(const float* __restrict__ Wf, const float* __restrict__ Wr,
                             const float* __restrict__ Wm,
                             u8* __restrict__ of, u8* __restrict__ orr, u8* __restrict__ om) {
  const int F4 = 2048 * 512 / 4;
  const int M4 = 4096 * 1024 / 4;
  int i = blockIdx.x * 256 + threadIdx.x;
  int stride = gridDim.x * 256;
  for (; i < 2 * F4 + M4; i += stride) {
    const float* src; unsigned* dst; int k;
    if (i < F4)          { src = Wf; dst = (unsigned*)of;  k = i; }
    else if (i < 2 * F4) { src = Wr; dst = (unsigned*)orr; k = i - F4; }
    else                 { src = Wm; dst = (unsigned*)om;  k = i - 2 * F4; }
    float4 f = ((const float4*)src)[k];
    unsigned w = pk2<false>(f.x, f.y, 0);
    w = pk2<true>(f.z, f.w, w);
    dst[k] = w;
  }
}

// E[v][n] = (v<66 ? Wih[n][v] : 0) + bias[n]  — LDS-tiled transpose, all 3 models.
__global__ __launch_bounds__(256) void build_E_all(
    const float* __restrict__ Wf, const float* __restrict__ bf,
    const float* __restrict__ Wr, const float* __restrict__ br,
    const float* __restrict__ Wm, const float* __restrict__ bm,
    float* __restrict__ Ef, float* __restrict__ Er, float* __restrict__ Em) {
  __shared__ float tile[64 * 67];
  int tb = blockIdx.x;
  const float* W; const float* bias; float* E; int H4; int n0;
  if (tb < 32)      { W = Wf; bias = bf; E = Ef; H4 = 2048; n0 = tb * 64; }
  else if (tb < 64) { W = Wr; bias = br; E = Er; H4 = 2048; n0 = (tb - 32) * 64; }
  else              { W = Wm; bias = bm; E = Em; H4 = 4096; n0 = (tb - 64) * 64; }
  const float* src = W + (size_t)n0 * IND;
  for (int i = threadIdx.x; i < 64 * IND; i += 256) {
    int n = i / IND, v = i - n * IND;
    tile[n * 67 + v] = src[i];
  }
  __syncthreads();
  int lane = threadIdx.x & 63, w = threadIdx.x >> 6;
  float bl = bias[n0 + lane];
  for (int v = w; v < 67; v += 4) {
    float val = (v < 66 ? tile[lane * 67 + v] : 0.f) + bl;
    E[(size_t)v * H4 + n0 + lane] = val;
  }
}

// Wcat: fp8 [160][1024]; rows 0..79 = W_sub (padded), 80..159 = W_ins
__global__ void pad_head_w(const float* __restrict__ Wsub, const float* __restrict__ Wins,
                           u8* __restrict__ Wcat) {
  int widx = blockIdx.x * 256 + threadIdx.x;  // one 4-byte word
  if (widx >= 160 * 256) return;
  int row = widx >> 8;
  int wc  = widx & 255;
  int srow = row < 80 ? row : row - 80;
  const float* W = row < 80 ? Wsub : Wins;
  float f0 = 0.f, f1 = 0.f, f2 = 0.f, f3 = 0.f;
  if (srow < 65) {
    const float* p = W + (size_t)srow * 1024 + wc * 4;
    f0 = p[0]; f1 = p[1]; f2 = p[2]; f3 = p[3];
  }
  unsigned w = pk2<false>(f0, f1, 0);
  w = pk2<true>(f2, f3, w);
  ((unsigned*)Wcat)[widx] = w;
}

// ---------------------------------------------------------------------------
// persistent LSTM: 512 blocks x 256 thr, 2 blocks/CU (exact-fit grid).
// Block = (batch chunk of 32) x (32 h-units, all 4 gates). ALL Whh weights
// VGPR-resident (fwd/rev 64 VGPR, mod 128 VGPR).
// Wave tile: 2 m-tiles x 2 n-tiles {(i,f) x 8 units | (g,o) x 8 units};
// shfl_xor(8) recombines gates (R4-proven epilogue).
// h via relaxed agent-scope atomics; ballot flag barrier per chunk-domain
// (mod: 32 producers, fwd/rev: 16).
// ---------------------------------------------------------------------------
template <int HH, int NS>
__device__ __forceinline__ void run_lstm(
    const u8* __restrict__ w8, const float* __restrict__ E,
    bool revr, u8* __restrict__ hall, int b0, int h0,
    unsigned* __restrict__ flags, int dom0, int myid,
    u8* __restrict__ alds, u8* __restrict__ hT, const u8* __restrict__ tok_small) {
  const int tid = threadIdx.x;
  const int lane = tid & 63, w = tid >> 6;
  const int lo = lane & 15, q = lane >> 4;
  constexpr int AST = HH + 8;          // padded LDS row stride (bytes)
  constexpr int U8C = HH / 8;
  constexpr int USH = (HH == 1024) ? 7 : 6;
  constexpr int NI  = (32 * U8C) / 256;   // 8 (fwd/rev) or 16 (mod)
  constexpr int NK  = HH / 32;
  const int hh = lo & 7;
  const bool hi = (lo >= 8);
  const int hu_e = h0 + w * 8 + hh;    // epilogue h-unit

  // B fragments: tile0 rows = gates{0,1} x units, tile1 = gates{2,3}
  long breg0[NK], breg1[NK];
  {
    const u8* brow0 = w8 + (size_t)((lo >> 3) * HH + hu_e) * HH + q * 8;
    const u8* brow1 = w8 + (size_t)((2 + (lo >> 3)) * HH + hu_e) * HH + q * 8;
#pragma unroll
    for (int kk = 0; kk < NK; ++kk) {
      breg0[kk] = *(const long*)(brow0 + kk * 32);
      breg1[kk] = *(const long*)(brow1 + kk * 32);
    }
  }
  float creg[4] = {0.f, 0.f, 0.f, 0.f};

  for (int t = 0; t < 34; ++t) {
    // ---- stage A-tile: batched relaxed-atomic loads -> regs -> LDS ----
    const u8* hsrc = hall + (size_t)t * (256 * HH);
    u64t tmp[NI];
#pragma unroll
    for (int ii = 0; ii < NI; ++ii) {
      int idx = tid + ii * 256;
      tmp[ii] = __hip_atomic_load(
          (const u64t*)(hsrc + (size_t)(b0 + (idx >> USH)) * HH + (idx & (U8C - 1)) * 8),
          __ATOMIC_RELAXED, __HIP_MEMORY_SCOPE_AGENT);
    }
#pragma unroll
    for (int ii = 0; ii < NI; ++ii) {
      int idx = tid + ii * 256;
      *(u64t*)&alds[(idx >> USH) * AST + (idx & (U8C - 1)) * 8] = tmp[ii];
    }
    __syncthreads();

    f32x4 acc[2][2];
#pragma unroll
    for (int mt = 0; mt < 2; ++mt) {
      acc[mt][0] = (f32x4){0.f, 0.f, 0.f, 0.f};
      acc[mt][1] = (f32x4){0.f, 0.f, 0.f, 0.f};
    }
    const u8* a0p = alds + lo * AST + q * 8;
    const u8* a1p = alds + (16 + lo) * AST + q * 8;
#pragma unroll
    for (int kk = 0; kk < NK; ++kk) {
      long a0 = *(const long*)(a0p + kk * 32);
      long a1 = *(const long*)(a1p + kk * 32);
      acc[0][0] = mfma_fp8(a0, breg0[kk], acc[0][0]);
      acc[0][1] = mfma_fp8(a0, breg1[kk], acc[0][1]);
      acc[1][0] = mfma_fp8(a1, breg0[kk], acc[1][0]);
      acc[1][1] = mfma_fp8(a1, breg1[kk], acc[1][1]);
    }

    // ---- epilogue: shfl_xor(8) gate recombine + E-gather + gate math ----
    int tpos = revr ? 33 - t : t;
    const u8* tkp = tok_small + tpos * 32;
#pragma unroll
    for (int mt = 0; mt < 2; ++mt) {
      f32x4 t0 = acc[mt][0], t1 = acc[mt][1];
      f32x4 p0, p1;
#pragma unroll
      for (int c2 = 0; c2 < 4; ++c2) {
        p0[c2] = __shfl_xor(t0[c2], 8, 64);
        p1[c2] = __shfl_xor(t1[c2], 8, 64);
      }
#pragma unroll
      for (int rr = 0; rr < 2; ++rr) {
        int r = (hi ? 2 : 0) + rr;
        float iv = hi ? p0[r] : t0[r];
        float fv = hi ? t0[r] : p0[r];
        float gv = hi ? p1[r] : t1[r];
        float ov = hi ? t1[r] : p1[r];
        int m = mt * 16 + q * 4 + r;
        int v = tkp[m];
        const float* e = E + (size_t)v * (4 * HH) + hu_e;
        iv += e[0]; fv += e[HH]; gv += e[2 * HH]; ov += e[3 * HH];
        float cold = creg[mt * 2 + rr];
        float cn = sigm(fv) * cold + sigm(iv) * tanhx(gv);
        float hn = sigm(ov) * tanhx(cn);
        creg[mt * 2 + rr] = cn;
        hT[m * 32 + w * 8 + hh] = (u8)(pk2<false>(hn, hn, 0) & 0xffu);
      }
    }
    __syncthreads();

    // ---- coalesced 4B agent store: thread -> (row m, 4-col chunk cc) ----
    {
      int m = tid >> 3, cc = tid & 7;
      unsigned val = *(const unsigned*)&hT[m * 32 + cc * 4];
      u8* hdst = hall + (size_t)(t + 1) * (256 * HH);
      __hip_atomic_store((unsigned*)(hdst + (size_t)(b0 + m) * HH + h0 + cc * 4),
                         val, __ATOMIC_RELAXED, __HIP_MEMORY_SCOPE_AGENT);
    }

    // ---- flag barrier: drain stores, fire flag, ballot poll ----
    if (t < 33) {
      __asm__ volatile("s_waitcnt vmcnt(0)" ::: "memory");
      __syncthreads();
      unsigned tgt = (unsigned)(t + 1);
      if (tid == 0)
        __hip_atomic_store(&flags[(dom0 + myid) * 32], tgt,
                           __ATOMIC_RELAXED, __HIP_MEMORY_SCOPE_AGENT);
      if (tid < NS) {
        int spin = 0;
        for (;;) {
          unsigned v = __hip_atomic_load(&flags[(dom0 + tid) * 32],
                                         __ATOMIC_RELAXED, __HIP_MEMORY_SCOPE_AGENT);
          if (__ballot(v < tgt) == 0) break;
          __builtin_amdgcn_s_sleep(1);
          if (++spin > (1 << 17)) break;   // safety exit
        }
      }
      __syncthreads();
    }
  }
}

__global__ __launch_bounds__(256, 2) void lstm_persist(
    const int* __restrict__ tok_x, const int* __restrict__ tok_y,
    const float* __restrict__ E_f, const u8* __restrict__ w8_f,
    const float* __restrict__ E_r, const u8* __restrict__ w8_r,
    const float* __restrict__ E_m, const u8* __restrict__ w8_m,
    u8* __restrict__ fwd_all, u8* __restrict__ rev_all, u8* __restrict__ y_all,
    unsigned* __restrict__ flags) {
  __shared__ u8 alds[32 * 1032];       // 33 KB A-stage (fwd/rev use 32*520)
  __shared__ u8 hT[32 * 32];           // store-transpose buffer
  __shared__ u8 tok_small[34 * 32];    // this block's tokens (66 = none)

  const int b = blockIdx.x;
  int role, c, s;
  if (b < 256)      { role = 2; c = b >> 5; s = b & 31; }          // mod: 256
  else if (b < 384) { int l = b - 256; role = 0; c = l >> 4; s = l & 15; }  // fwd
  else              { int l = b - 384; role = 1; c = l >> 4; s = l & 15; }  // rev

  const float* E  = role == 0 ? E_f  : role == 1 ? E_r  : E_m;
  const u8*    w8 = role == 0 ? w8_f : role == 1 ? w8_r : w8_m;
  u8* hall        = role == 0 ? fwd_all : role == 1 ? rev_all : y_all;
  const int* tokg = (role == 2) ? tok_y : tok_x;
  const int b0 = c * 32;
  const int h0 = s * 32;
  const int dom0 = (role == 2) ? c * 32 : (role == 0) ? 256 + c * 16 : 384 + c * 16;

  for (int i = threadIdx.x; i < 34 * 32; i += 256) {
    int t2 = i >> 5, m = i & 31;
    int tk = tokg[t2 * 256 + b0 + m];
    tok_small[i] = (u8)(tk < 0 ? 66 : tk);
  }
  __syncthreads();

  if (role == 2)
    run_lstm<1024, 32>(w8, E, false, hall, b0, h0, flags, dom0, s, alds, hT, tok_small);
  else
    run_lstm<512, 16>(w8, E, role == 1, hall, b0, h0, flags, dom0, s, alds, hT, tok_small);
}

// ---------------------------------------------------------------------------
// head: lx = x_emb @ W^T, ly = y_emb @ W^T + b, both heads (W rows 0..159).
// 136 blocks x 256 thr; A-loads issued BEFORE W staging (latency overlap).
// ---------------------------------------------------------------------------
__global__ __launch_bounds__(256, 1) void head_kernel(
    const u8* __restrict__ fwd_all, const u8* __restrict__ rev_all,
    const u8* __restrict__ y_all, const u8* __restrict__ Wcat,
    const float* __restrict__ b_sub, const float* __restrict__ b_ins,
    float* __restrict__ lx_sub, float* __restrict__ lx_ins,
    float* __restrict__ ly_sub, float* __restrict__ ly_ins) {
  __shared__ u8 wq[160 * 264];   // 42240 B, row pad 264 for bank spread
  const int lane = threadIdx.x & 63, wave = threadIdx.x >> 6;
  const int lo = lane & 15, q = lane >> 4;
  int blk = blockIdx.x;
  bool yside = (blk >= 68);
  int mb = yside ? blk - 68 : blk;
  int ij = mb >> 1;
  int bbase = (mb & 1) * 128;

  f32x4 acc[2][10];
#pragma unroll
  for (int mt = 0; mt < 2; ++mt)
#pragma unroll
    for (int nn = 0; nn < 10; ++nn) acc[mt][nn] = (f32x4){0.f,0.f,0.f,0.f};

  for (int qk = 0; qk < 4; ++qk) {
    // A-fragment loads first (independent of LDS) -> overlap with staging
    long aA[2][8];
#pragma unroll
    for (int mt = 0; mt < 2; ++mt) {
      int row = bbase + wave * 32 + mt * 16 + lo;
      const u8* ab;
      if (yside)
        ab = y_all + ((size_t)(ij + 1) * 256 + row) * 1024 + qk * 256 + q * 8;
      else if (qk < 2)
        ab = fwd_all + ((size_t)(ij + 1) * 256 + row) * 512 + qk * 256 + q * 8;
      else
        ab = rev_all + ((size_t)(34 - ij) * 256 + row) * 512 + (qk - 2) * 256 + q * 8;
#pragma unroll
      for (int ki = 0; ki < 8; ++ki) aA[mt][ki] = *(const long*)(ab + ki * 32);
    }

    for (int c8 = threadIdx.x; c8 < 160 * 32; c8 += 256) {
      int row = c8 >> 5, col = (c8 & 31) << 3;
      *(long*)&wq[row * 264 + col] =
          *(const long*)&Wcat[(size_t)row * 1024 + qk * 256 + col];
    }
    __syncthreads();

#pragma unroll
    for (int ki = 0; ki < 8; ++ki) {
#pragma unroll
      for (int nn = 0; nn < 10; ++nn) {
        long bf = *(const long*)&wq[(nn * 16 + lo) * 264 + ki * 32 + q * 8];
        acc[0][nn] = mfma_fp8(aA[0][ki], bf, acc[0][nn]);
        acc[1][nn] = mfma_fp8(aA[1][ki], bf, acc[1][nn]);
      }
    }
    __syncthreads();
  }

#pragma unroll
  for (int mt = 0; mt < 2; ++mt) {
#pragma unroll
    for (int nn = 0; nn < 10; ++nn) {
      bool is_sub = (nn < 5);
      int n = (is_sub ? nn : nn - 5) * 16 + lo;
      float bias = 0.0f;
      if (yside && n < 65) bias = is_sub ? b_sub[n] : b_ins[n];
      float* dst = yside ? (is_sub ? ly_sub : ly_ins) : (is_sub ? lx_sub : lx_ins);
#pragma unroll
      for (int r = 0; r < 4; ++r) {
        int b = bbase + wave * 32 + mt * 16 + q * 4 + r;
        dst[((size_t)ij * 256 + b) * OP_ + n] = acc[mt][nn][r] + bias;
      }
    }
  }
}

// ---------------------------------------------------------------------------
// pair: per (i,j,b) logsumexp over 65 of lx+ly for both heads.
// 136 blocks (34 i x 4 b-chunks) x 256 thr (64 b x 4 j-lanes); lx in regs.
// ---------------------------------------------------------------------------
__device__ __forceinline__ void lse_regs(const float4* __restrict__ X,
                                         const float* __restrict__ py, int sym,
                                         float& logZ, float& v64, float& vs) {
  const float4* py4 = (const float4*)py;
  float4 Y[17];
#pragma unroll
  for (int q = 0; q < 17; ++q) Y[q] = py4[q];
  float mm = -3.4e38f;
#pragma unroll
  for (int q = 0; q < 17; ++q) {
    float vx[4] = {X[q].x + Y[q].x, X[q].y + Y[q].y, X[q].z + Y[q].z, X[q].w + Y[q].w};
#pragma unroll
    for (int c = 0; c < 4; ++c) {
      int o = q * 4 + c;
      if (o < 65) mm = fmaxf(mm, vx[c]);
    }
  }
  float ss = 0.f, vsl = 0.f, vend = 0.f;
#pragma unroll
  for (int q = 0; q < 17; ++q) {
    float vx[4] = {X[q].x + Y[q].x, X[q].y + Y[q].y, X[q].z + Y[q].z, X[q].w + Y[q].w};
#pragma unroll
    for (int c = 0; c < 4; ++c) {
      int o = q * 4 + c;
      if (o < 65) {
        ss += __expf(vx[c] - mm);
        if (o == 64) vend = vx[c];
        if (o == sym) vsl = vx[c];
      }
    }
  }
  logZ = mm + __logf(ss);
  v64 = vend;
  vs = vsl;
}

__global__ __launch_bounds__(256, 1) void pair_kernel(
    const int* __restrict__ tok_x, const int* __restrict__ tok_y,
    const float* __restrict__ lx_sub, const float* __restrict__ lx_ins,
    const float* __restrict__ ly_sub, const float* __restrict__ ly_ins,
    float* __restrict__ out) {
  const int i = blockIdx.x >> 2;
  const int bc = blockIdx.x & 3;
  const int jq = threadIdx.x >> 6;
  const int bl = threadIdx.x & 63;
  const int b = bc * 64 + bl;
  const size_t CH = (size_t)SX_ * SY_ * B_;

  float4 Xs[17], Xi[17];
  {
    const float4* ps = (const float4*)(lx_sub + ((size_t)i * 256 + b) * OP_);
    const float4* pi = (const float4*)(lx_ins + ((size_t)i * 256 + b) * OP_);
#pragma unroll
    for (int q = 0; q < 17; ++q) { Xs[q] = ps[q]; Xi[q] = pi[q]; }
  }
  int tx = tok_x[i * 256 + b];

  for (int j = jq; j < 34; j += 4) {
    size_t obase = ((size_t)i * SY_ + j) * 256 + b;
    bool dead = (j == SY_ - 1) || (tx < 0);
    if (!dead) {
      int ty = tok_y[j * 256 + b];
      if (ty < 0) dead = true;
    }
    if (dead) {
      out[obase] = BIG_NEG;
      out[CH + obase] = BIG_NEG;
      out[2 * CH + obase] = BIG_NEG;
      out[3 * CH + obase] = BIG_NEG;
      continue;
    }
    int tn = tok_y[(j + 1) * 256 + b];
    bool ins_ok = (tn != 65);
    int sym = (tn >= 0 && tn < 64) ? tn : -1;

    float logZs, v64s, vss;
    lse_regs(Xs, ly_sub + ((size_t)j * 256 + b) * OP_, sym, logZs, v64s, vss);
    float dlt = v64s - logZs;
    float sub_val = (sym >= 0) ? (vss - logZs) : 0.0f;

    float logZi, v64i, vsi;
    lse_regs(Xi, ly_ins + ((size_t)j * 256 + b) * OP_, sym, logZi, v64i, vsi);
    float endv = v64i - logZi;
    float ins_val = (sym >= 0) ? (vsi - logZi) : 0.0f;

    out[obase]          = ins_ok ? ins_val : BIG_NEG;
    out[CH + obase]     = ins_ok ? sub_val : BIG_NEG;
    out[2 * CH + obase] = endv;
    out[3 * CH + obase] = dlt;
  }
}

// ---------------------------------------------------------------------------
// launch
// ---------------------------------------------------------------------------
extern "C" void kernel_launch(void* const* d_in, const int* in_sizes, int n_in,
                              void* d_out, int out_size, void* d_ws, size_t ws_size,
                              hipStream_t stream) {
  const float* sources = (const float*)d_in[0];
  const float* targets = (const float*)d_in[1];
  const float* Wih_f = (const float*)d_in[2];
  const float* Whh_f = (const float*)d_in[3];
  const float* b_f   = (const float*)d_in[4];
  const float* Wih_r = (const float*)d_in[5];
  const float* Whh_r = (const float*)d_in[6];
  const float* b_r   = (const float*)d_in[7];
  const float* Wih_m = (const float*)d_in[8];
  const float* Whh_m = (const float*)d_in[9];
  const float* b_m   = (const float*)d_in[10];
  const float* W_sub = (const float*)d_in[11];
  const float* b_sub = (const float*)d_in[12];
  const float* W_ins = (const float*)d_in[13];
  const float* b_ins = (const float*)d_in[14];
  float* out = (float*)d_out;

  char* w = (char*)d_ws;
  constexpr size_t FLAG_SZ = 512 * 32 * 4;                  // 64 KB, 128B-spread
  constexpr size_t TOK_SZ  = (size_t)SX_ * B_ * 4;
  constexpr size_t WCAT_SZ = (size_t)160 * 1024;            // head W fp8
  constexpr size_t W8F_SZ  = (size_t)2048 * 512;            // fwd Whh fp8
  constexpr size_t W8M_SZ  = (size_t)4096 * 1024;           // mod Whh fp8
  constexpr size_t EF_SZ   = (size_t)67 * 2048 * 4;         // E tables f32
  constexpr size_t EM_SZ   = (size_t)67 * 4096 * 4;
  constexpr size_t LX_SZ   = (size_t)SX_ * B_ * OP_ * 4;
  constexpr size_t HF_SZ   = (size_t)35 * B_ * 512;         // h slabs fp8
  constexpr size_t HM_SZ   = (size_t)35 * B_ * 1024;

  size_t off = 0;
  unsigned* flags = (unsigned*)(w + off); off += FLAG_SZ;
  int*  tok_x   = (int*)(w + off);  off += TOK_SZ;
  int*  tok_y   = (int*)(w + off);  off += TOK_SZ;
  off = (off + 255) & ~(size_t)255;
  u8*   Wcat    = (u8*)(w + off);   off += WCAT_SZ;
  u8*   w8_f    = (u8*)(w + off);   off += W8F_SZ;
  u8*   w8_r    = (u8*)(w + off);   off += W8F_SZ;
  u8*   w8_m    = (u8*)(w + off);   off += W8M_SZ;
  float* E_f    = (float*)(w + off); off += EF_SZ;
  float* E_r    = (float*)(w + off); off += EF_SZ;
  float* E_m    = (float*)(w + off); off += EM_SZ;
  float* lx_sub = (float*)(w + off); off += LX_SZ;
  float* lx_ins = (float*)(w + off); off += LX_SZ;
  float* ly_sub = (float*)(w + off); off += LX_SZ;
  float* ly_ins = (float*)(w + off); off += LX_SZ;
  u8* fwd_all   = (u8*)(w + off);   off += HF_SZ;
  u8* rev_all   = (u8*)(w + off);   off += HF_SZ;
  u8* y_all     = (u8*)(w + off);   off += HM_SZ;
  (void)ws_size; (void)in_sizes; (void)n_in; (void)out_size;

  // zero: flags + t=0 h slabs
  (void)hipMemsetAsync(flags, 0, FLAG_SZ, stream);
  (void)hipMemsetAsync(fwd_all, 0, (size_t)B_ * 512, stream);
  (void)hipMemsetAsync(rev_all, 0, (size_t)B_ * 512, stream);
  (void)hipMemsetAsync(y_all,   0, (size_t)B_ * 1024, stream);

  decode_tokens<<<(2 * SX_ * B_ + 255) / 256, 256, 0, stream>>>(sources, targets, tok_x, tok_y);
  pad_head_w<<<160, 256, 0, stream>>>(W_sub, W_ins, Wcat);
  conv_fp8_all<<<3072, 256, 0, stream>>>(Whh_f, Whh_r, Whh_m, w8_f, w8_r, w8_m);
  build_E_all<<<128, 256, 0, stream>>>(Wih_f, b_f, Wih_r, b_r, Wih_m, b_m, E_f, E_r, E_m);

  lstm_persist<<<512, 256, 0, stream>>>(
      tok_x, tok_y,
      E_f, w8_f,
      E_r, w8_r,
      E_m, w8_m,
      fwd_all, rev_all, y_all, flags);

  head_kernel<<<136, 256, 0, stream>>>(fwd_all, rev_all, y_all, Wcat,
                                       b_sub, b_ins, lx_sub, lx_ins, ly_sub, ly_ins);

  pair_kernel<<<136, 256, 0, stream>>>(tok_x, tok_y, lx_sub, lx_ins,
                                       ly_sub, ly_ins, out);
}

// Round 10
// 339.257 us; speedup vs baseline: 2.0655x; 1.0922x over previous
//
#include <hip/hip_runtime.h>

typedef __attribute__((ext_vector_type(4))) float f32x4;
typedef unsigned char u8;
typedef unsigned long long u64t;

#define BIG_NEG -1000000000.0f

static constexpr int B_  = 256;
static constexpr int SX_ = 34;
static constexpr int SY_ = 34;
static constexpr int IND = 66;   // IN_DIM
static constexpr int OP_ = 80;   // padded OUT_DIM (65 -> 80)

__device__ __forceinline__ f32x4 mfma_fp8(long a, long b, f32x4 c) {
  return __builtin_amdgcn_mfma_f32_16x16x32_fp8_fp8(a, b, c, 0, 0, 0);
}
__device__ __forceinline__ float sigm(float x)  { return 1.0f / (1.0f + __expf(-x)); }
__device__ __forceinline__ float tanhx(float x) { return 2.0f * sigm(2.0f * x) - 1.0f; }
template <bool HI>
__device__ __forceinline__ unsigned pk2(float a, float b, unsigned old) {
  return __builtin_amdgcn_cvt_pk_fp8_f32(a, b, (int)old, HI);
}

// ---------------------------------------------------------------------------
// fused prep kernel: blocks [0,68) decode | [68,228) pad_head |
// [228,356) build_E | [356,3428) conv_fp8 (grid-stride)
// ---------------------------------------------------------------------------
__global__ __launch_bounds__(256) void prep_all(
    const float* __restrict__ src, const float* __restrict__ tgt,
    int* __restrict__ tok_x, int* __restrict__ tok_y,
    const float* __restrict__ Wsub, const float* __restrict__ Wins,
    u8* __restrict__ Wcat,
    const float* __restrict__ Wihf, const float* __restrict__ bf,
    const float* __restrict__ Wihr, const float* __restrict__ br,
    const float* __restrict__ Wihm, const float* __restrict__ bm,
    float* __restrict__ Ef, float* __restrict__ Er, float* __restrict__ Em,
    const float* __restrict__ Whf, const float* __restrict__ Whr,
    const float* __restrict__ Whm,
    u8* __restrict__ w8f, u8* __restrict__ w8r, u8* __restrict__ w8m) {
  __shared__ float tile[64 * 67];
  const int blk = blockIdx.x;
  const int tid = threadIdx.x;

  if (blk < 68) {                       // ---- decode tokens ----
    int idx = blk * 256 + tid;
    const int half = SX_ * B_;
    const float* base = (idx < half) ? src : tgt;
    int* outp         = (idx < half) ? tok_x : tok_y;
    int k = (idx < half) ? idx : idx - half;
    const float* p = base + (size_t)k * IND;
    int tok = -1;
    for (int v = 0; v < IND; ++v) if (p[v] > 0.5f) tok = v;
    outp[k] = tok;
  } else if (blk < 228) {               // ---- pad head W -> fp8 ----
    int widx = (blk - 68) * 256 + tid;
    int row = widx >> 8;
    int wc  = widx & 255;
    int srow = row < 80 ? row : row - 80;
    const float* W = row < 80 ? Wsub : Wins;
    float f0 = 0.f, f1 = 0.f, f2 = 0.f, f3 = 0.f;
    if (srow < 65) {
      const float* p = W + (size_t)srow * 1024 + wc * 4;
      f0 = p[0]; f1 = p[1]; f2 = p[2]; f3 = p[3];
    }
    unsigned w = pk2<false>(f0, f1, 0);
    w = pk2<true>(f2, f3, w);
    ((unsigned*)Wcat)[widx] = w;
  } else if (blk < 356) {               // ---- build E (LDS transpose) ----
    int tb = blk - 228;
    const float* W; const float* bias; float* E; int H4; int n0;
    if (tb < 32)      { W = Wihf; bias = bf; E = Ef; H4 = 2048; n0 = tb * 64; }
    else if (tb < 64) { W = Wihr; bias = br; E = Er; H4 = 2048; n0 = (tb - 32) * 64; }
    else              { W = Wihm; bias = bm; E = Em; H4 = 4096; n0 = (tb - 64) * 64; }
    const float* s2 = W + (size_t)n0 * IND;
    for (int i = tid; i < 64 * IND; i += 256) {
      int n = i / IND, v = i - n * IND;
      tile[n * 67 + v] = s2[i];
    }
    __syncthreads();
    int lane = tid & 63, w2 = tid >> 6;
    float bl = bias[n0 + lane];
    for (int v = w2; v < 67; v += 4) {
      float val = (v < 66 ? tile[lane * 67 + v] : 0.f) + bl;
      E[(size_t)v * H4 + n0 + lane] = val;
    }
  } else {                              // ---- conv Whh -> fp8 ----
    const int F4 = 2048 * 512 / 4;
    const int M4 = 4096 * 1024 / 4;
    int i = (blk - 356) * 256 + tid;
    int stride = 3072 * 256;
    for (; i < 2 * F4 + M4; i += stride) {
      const float* s3; unsigned* dst; int k;
      if (i < F4)          { s3 = Whf; dst = (unsigned*)w8f; k = i; }
      else if (i < 2 * F4) { s3 = Whr; dst = (unsigned*)w8r; k = i - F4; }
      else                 { s3 = Whm; dst = (unsigned*)w8m; k = i - 2 * F4; }
      float4 f = ((const float4*)s3)[k];
      unsigned w3 = pk2<false>(f.x, f.y, 0);
      w3 = pk2<true>(f.z, f.w, w3);
      dst[k] = w3;
    }
  }
}

// ---------------------------------------------------------------------------
// persistent LSTM: 512 blocks x 256 thr, 2 blocks/CU (exact-fit grid).
// Block = (batch chunk of 32) x (32 h-units, all 4 gates).
// t=0: h0 == 0 -> skip staging + MFMA entirely (no memset needed).
// h via relaxed agent-scope atomics; ballot flag barrier per chunk-domain.
// ---------------------------------------------------------------------------
template <int HH, int NS>
__device__ __forceinline__ void run_lstm(
    const u8* __restrict__ w8, const float* __restrict__ E,
    bool revr, u8* __restrict__ hall, int b0, int h0,
    unsigned* __restrict__ flags, int dom0, int myid,
    u8* __restrict__ alds, u8* __restrict__ hT, const u8* __restrict__ tok_small) {
  const int tid = threadIdx.x;
  const int lane = tid & 63, w = tid >> 6;
  const int lo = lane & 15, q = lane >> 4;
  constexpr int AST = HH + 8;          // padded LDS row stride (bytes)
  constexpr int U8C = HH / 8;
  constexpr int USH = (HH == 1024) ? 7 : 6;
  constexpr int NI  = (32 * U8C) / 256;   // 8 (fwd/rev) or 16 (mod)
  constexpr int NK  = HH / 32;
  const int hh = lo & 7;
  const bool hi = (lo >= 8);
  const int hu_e = h0 + w * 8 + hh;    // epilogue h-unit

  // B fragments: tile0 rows = gates{0,1} x units, tile1 = gates{2,3}
  long breg0[NK], breg1[NK];
  {
    const u8* brow0 = w8 + (size_t)((lo >> 3) * HH + hu_e) * HH + q * 8;
    const u8* brow1 = w8 + (size_t)((2 + (lo >> 3)) * HH + hu_e) * HH + q * 8;
#pragma unroll
    for (int kk = 0; kk < NK; ++kk) {
      breg0[kk] = *(const long*)(brow0 + kk * 32);
      breg1[kk] = *(const long*)(brow1 + kk * 32);
    }
  }
  float creg[4] = {0.f, 0.f, 0.f, 0.f};

  for (int t = 0; t < 34; ++t) {
    f32x4 acc[2][2];
#pragma unroll
    for (int mt = 0; mt < 2; ++mt) {
      acc[mt][0] = (f32x4){0.f, 0.f, 0.f, 0.f};
      acc[mt][1] = (f32x4){0.f, 0.f, 0.f, 0.f};
    }

    if (t > 0) {
      // ---- stage A-tile: batched relaxed-atomic loads -> regs -> LDS ----
      const u8* hsrc = hall + (size_t)t * (256 * HH);
      u64t tmp[NI];
#pragma unroll
      for (int ii = 0; ii < NI; ++ii) {
        int idx = tid + ii * 256;
        tmp[ii] = __hip_atomic_load(
            (const u64t*)(hsrc + (size_t)(b0 + (idx >> USH)) * HH + (idx & (U8C - 1)) * 8),
            __ATOMIC_RELAXED, __HIP_MEMORY_SCOPE_AGENT);
      }
#pragma unroll
      for (int ii = 0; ii < NI; ++ii) {
        int idx = tid + ii * 256;
        *(u64t*)&alds[(idx >> USH) * AST + (idx & (U8C - 1)) * 8] = tmp[ii];
      }
      __syncthreads();

      const u8* a0p = alds + lo * AST + q * 8;
      const u8* a1p = alds + (16 + lo) * AST + q * 8;
#pragma unroll
      for (int kk = 0; kk < NK; ++kk) {
        long a0 = *(const long*)(a0p + kk * 32);
        long a1 = *(const long*)(a1p + kk * 32);
        acc[0][0] = mfma_fp8(a0, breg0[kk], acc[0][0]);
        acc[0][1] = mfma_fp8(a0, breg1[kk], acc[0][1]);
        acc[1][0] = mfma_fp8(a1, breg0[kk], acc[1][0]);
        acc[1][1] = mfma_fp8(a1, breg1[kk], acc[1][1]);
      }
    }

    // ---- epilogue: shfl_xor(8) gate recombine + E-gather + gate math ----
    int tpos = revr ? 33 - t : t;
    const u8* tkp = tok_small + tpos * 32;
#pragma unroll
    for (int mt = 0; mt < 2; ++mt) {
      f32x4 t0 = acc[mt][0], t1 = acc[mt][1];
      f32x4 p0, p1;
#pragma unroll
      for (int c2 = 0; c2 < 4; ++c2) {
        p0[c2] = __shfl_xor(t0[c2], 8, 64);
        p1[c2] = __shfl_xor(t1[c2], 8, 64);
      }
#pragma unroll
      for (int rr = 0; rr < 2; ++rr) {
        int r = (hi ? 2 : 0) + rr;
        float iv = hi ? p0[r] : t0[r];
        float fv = hi ? t0[r] : p0[r];
        float gv = hi ? p1[r] : t1[r];
        float ov = hi ? t1[r] : p1[r];
        int m = mt * 16 + q * 4 + r;
        int v = tkp[m];
        const float* e = E + (size_t)v * (4 * HH) + hu_e;
        iv += e[0]; fv += e[HH]; gv += e[2 * HH]; ov += e[3 * HH];
        float cold = creg[mt * 2 + rr];
        float cn = sigm(fv) * cold + sigm(iv) * tanhx(gv);
        float hn = sigm(ov) * tanhx(cn);
        creg[mt * 2 + rr] = cn;
        hT[m * 32 + w * 8 + hh] = (u8)(pk2<false>(hn, hn, 0) & 0xffu);
      }
    }
    __syncthreads();

    // ---- coalesced 4B agent store: thread -> (row m, 4-col chunk cc) ----
    {
      int m = tid >> 3, cc = tid & 7;
      unsigned val = *(const unsigned*)&hT[m * 32 + cc * 4];
      u8* hdst = hall + (size_t)(t + 1) * (256 * HH);
      __hip_atomic_store((unsigned*)(hdst + (size_t)(b0 + m) * HH + h0 + cc * 4),
                         val, __ATOMIC_RELAXED, __HIP_MEMORY_SCOPE_AGENT);
    }

    // ---- flag barrier: drain stores, fire flag, ballot poll ----
    if (t < 33) {
      __asm__ volatile("s_waitcnt vmcnt(0)" ::: "memory");
      __syncthreads();
      unsigned tgt = (unsigned)(t + 1);
      if (tid == 0)
        __hip_atomic_store(&flags[(dom0 + myid) * 32], tgt,
                           __ATOMIC_RELAXED, __HIP_MEMORY_SCOPE_AGENT);
      if (tid < NS) {
        int spin = 0;
        for (;;) {
          unsigned v = __hip_atomic_load(&flags[(dom0 + tid) * 32],
                                         __ATOMIC_RELAXED, __HIP_MEMORY_SCOPE_AGENT);
          if (__ballot(v < tgt) == 0) break;
          __builtin_amdgcn_s_sleep(1);
          if (++spin > (1 << 17)) break;   // safety exit
        }
      }
      __syncthreads();
    }
  }
}

__global__ __launch_bounds__(256, 2) void lstm_persist(
    const int* __restrict__ tok_x, const int* __restrict__ tok_y,
    const float* __restrict__ E_f, const u8* __restrict__ w8_f,
    const float* __restrict__ E_r, const u8* __restrict__ w8_r,
    const float* __restrict__ E_m, const u8* __restrict__ w8_m,
    u8* __restrict__ fwd_all, u8* __restrict__ rev_all, u8* __restrict__ y_all,
    unsigned* __restrict__ flags) {
  __shared__ u8 alds[32 * 1032];       // 33 KB A-stage (fwd/rev use 32*520)
  __shared__ u8 hT[32 * 32];           // store-transpose buffer
  __shared__ u8 tok_small[34 * 32];    // this block's tokens (66 = none)

  const int b = blockIdx.x;
  int role, c, s;
  if (b < 256)      { role = 2; c = b >> 5; s = b & 31; }          // mod: 256
  else if (b < 384) { int l = b - 256; role = 0; c = l >> 4; s = l & 15; }  // fwd
  else              { int l = b - 384; role = 1; c = l >> 4; s = l & 15; }  // rev

  const float* E  = role == 0 ? E_f  : role == 1 ? E_r  : E_m;
  const u8*    w8 = role == 0 ? w8_f : role == 1 ? w8_r : w8_m;
  u8* hall        = role == 0 ? fwd_all : role == 1 ? rev_all : y_all;
  const int* tokg = (role == 2) ? tok_y : tok_x;
  const int b0 = c * 32;
  const int h0 = s * 32;
  const int dom0 = (role == 2) ? c * 32 : (role == 0) ? 256 + c * 16 : 384 + c * 16;

  for (int i = threadIdx.x; i < 34 * 32; i += 256) {
    int t2 = i >> 5, m = i & 31;
    int tk = tokg[t2 * 256 + b0 + m];
    tok_small[i] = (u8)(tk < 0 ? 66 : tk);
  }
  __syncthreads();

  if (role == 2)
    run_lstm<1024, 32>(w8, E, false, hall, b0, h0, flags, dom0, s, alds, hT, tok_small);
  else
    run_lstm<512, 16>(w8, E, role == 1, hall, b0, h0, flags, dom0, s, alds, hT, tok_small);
}

// ---------------------------------------------------------------------------
// head: lx = x_emb @ W^T, ly = y_emb @ W^T + b, both heads (W rows 0..159).
// 272 blocks x 256 thr; 64 rows/block (1 m-tile/wave); A-loads before W-stage.
// ---------------------------------------------------------------------------
__global__ __launch_bounds__(256, 1) void head_kernel(
    const u8* __restrict__ fwd_all, const u8* __restrict__ rev_all,
    const u8* __restrict__ y_all, const u8* __restrict__ Wcat,
    const float* __restrict__ b_sub, const float* __restrict__ b_ins,
    float* __restrict__ lx_sub, float* __restrict__ lx_ins,
    float* __restrict__ ly_sub, float* __restrict__ ly_ins) {
  __shared__ u8 wq[160 * 264];   // 42240 B, row pad 264 for bank spread
  const int lane = threadIdx.x & 63, wave = threadIdx.x >> 6;
  const int lo = lane & 15, q = lane >> 4;
  int blk = blockIdx.x;
  bool yside = (blk >= 136);
  int mb = yside ? blk - 136 : blk;
  int ij = mb >> 2;
  int bbase = (mb & 3) * 64;

  f32x4 acc[10];
#pragma unroll
  for (int nn = 0; nn < 10; ++nn) acc[nn] = (f32x4){0.f,0.f,0.f,0.f};

  for (int qk = 0; qk < 4; ++qk) {
    // A-fragment loads first (independent of LDS) -> overlap with staging
    long aA[8];
    {
      int row = bbase + wave * 16 + lo;
      const u8* ab;
      if (yside)
        ab = y_all + ((size_t)(ij + 1) * 256 + row) * 1024 + qk * 256 + q * 8;
      else if (qk < 2)
        ab = fwd_all + ((size_t)(ij + 1) * 256 + row) * 512 + qk * 256 + q * 8;
      else
        ab = rev_all + ((size_t)(34 - ij) * 256 + row) * 512 + (qk - 2) * 256 + q * 8;
#pragma unroll
      for (int ki = 0; ki < 8; ++ki) aA[ki] = *(const long*)(ab + ki * 32);
    }

    for (int c8 = threadIdx.x; c8 < 160 * 32; c8 += 256) {
      int row = c8 >> 5, col = (c8 & 31) << 3;
      *(long*)&wq[row * 264 + col] =
          *(const long*)&Wcat[(size_t)row * 1024 + qk * 256 + col];
    }
    __syncthreads();

#pragma unroll
    for (int ki = 0; ki < 8; ++ki) {
#pragma unroll
      for (int nn = 0; nn < 10; ++nn) {
        long bf = *(const long*)&wq[(nn * 16 + lo) * 264 + ki * 32 + q * 8];
        acc[nn] = mfma_fp8(aA[ki], bf, acc[nn]);
      }
    }
    __syncthreads();
  }

#pragma unroll
  for (int nn = 0; nn < 10; ++nn) {
    bool is_sub = (nn < 5);
    int n = (is_sub ? nn : nn - 5) * 16 + lo;
    float bias = 0.0f;
    if (yside && n < 65) bias = is_sub ? b_sub[n] : b_ins[n];
    float* dst = yside ? (is_sub ? ly_sub : ly_ins) : (is_sub ? lx_sub : lx_ins);
#pragma unroll
    for (int r = 0; r < 4; ++r) {
      int b = bbase + wave * 16 + q * 4 + r;
      dst[((size_t)ij * 256 + b) * OP_ + n] = acc[nn][r] + bias;
    }
  }
}

// ---------------------------------------------------------------------------
// pair: split by HEAD to kill register spill. grid 272 = head{sub,ins} x 34 i
// x 4 b-chunks; block 256 thr (64 b x 4 j-lanes). X (one head) in regs.
//   sub pass -> ch1 (sub), ch3 (del);  ins pass -> ch0 (ins), ch2 (end)
// ---------------------------------------------------------------------------
__device__ __forceinline__ void lse_one(const float4* __restrict__ X,
                                        const float* __restrict__ py, int sym,
                                        float& logZ, float& v64, float& vs) {
  float v[68];
  const float4* py4 = (const float4*)py;
#pragma unroll
  for (int q = 0; q < 17; ++q) {
    float4 yb = py4[q];
    v[4 * q + 0] = X[q].x + yb.x;
    v[4 * q + 1] = X[q].y + yb.y;
    v[4 * q + 2] = X[q].z + yb.z;
    v[4 * q + 3] = X[q].w + yb.w;
  }
  float m = v[0];
#pragma unroll
  for (int o = 1; o < 65; ++o) m = fmaxf(m, v[o]);
  float s = 0.0f, vsl = 0.0f;
#pragma unroll
  for (int o = 0; o < 65; ++o) {
    s += __expf(v[o] - m);
    if (o < 64) vsl = (o == sym) ? v[o] : vsl;
  }
  logZ = m + __logf(s);
  v64 = v[64];
  vs = vsl;
}

__global__ __launch_bounds__(256, 1) void pair_kernel(
    const int* __restrict__ tok_x, const int* __restrict__ tok_y,
    const float* __restrict__ lx_sub, const float* __restrict__ lx_ins,
    const float* __restrict__ ly_sub, const float* __restrict__ ly_ins,
    float* __restrict__ out) {
  const int hsel = blockIdx.x >= 136;
  const int rem = hsel ? blockIdx.x - 136 : blockIdx.x;
  const int i = rem >> 2;
  const int bc = rem & 3;
  const int jq = threadIdx.x >> 6;
  const int bl = threadIdx.x & 63;
  const int b = bc * 64 + bl;
  const size_t CH = (size_t)SX_ * SY_ * B_;
  const float* lx = hsel ? lx_ins : lx_sub;
  const float* ly = hsel ? ly_ins : ly_sub;
  // sub: chA=1 (sub), chB=3 (del); ins: chA=0 (ins), chB=2 (end)
  float* outA = out + (hsel ? 0 : CH);
  float* outB = out + (hsel ? 2 * CH : 3 * CH);

  float4 X[17];
  {
    const float4* ps = (const float4*)(lx + ((size_t)i * 256 + b) * OP_);
#pragma unroll
    for (int q = 0; q < 17; ++q) X[q] = ps[q];
  }
  int tx = tok_x[i * 256 + b];

  for (int j = jq; j < 34; j += 4) {
    size_t obase = ((size_t)i * SY_ + j) * 256 + b;
    bool dead = (j == SY_ - 1) || (tx < 0);
    if (!dead) {
      int ty = tok_y[j * 256 + b];
      if (ty < 0) dead = true;
    }
    if (dead) {
      outA[obase] = BIG_NEG;
      outB[obase] = BIG_NEG;
      continue;
    }
    int tn = tok_y[(j + 1) * 256 + b];
    bool ins_ok = (tn != 65);
    int sym = (tn >= 0 && tn < 64) ? tn : -1;

    float logZ, v64, vs;
    lse_one(X, ly + ((size_t)j * 256 + b) * OP_, sym, logZ, v64, vs);
    float valB = v64 - logZ;                       // del (sub) / end (ins)
    float valA = (sym >= 0) ? (vs - logZ) : 0.0f;  // sub / ins value
    outA[obase] = ins_ok ? valA : BIG_NEG;
    outB[obase] = valB;
  }
}

// ---------------------------------------------------------------------------
// launch
// ---------------------------------------------------------------------------
extern "C" void kernel_launch(void* const* d_in, const int* in_sizes, int n_in,
                              void* d_out, int out_size, void* d_ws, size_t ws_size,
                              hipStream_t stream) {
  const float* sources = (const float*)d_in[0];
  const float* targets = (const float*)d_in[1];
  const float* Wih_f = (const float*)d_in[2];
  const float* Whh_f = (const float*)d_in[3];
  const float* b_f   = (const float*)d_in[4];
  const float* Wih_r = (const float*)d_in[5];
  const float* Whh_r = (const float*)d_in[6];
  const float* b_r   = (const float*)d_in[7];
  const float* Wih_m = (const float*)d_in[8];
  const float* Whh_m = (const float*)d_in[9];
  const float* b_m   = (const float*)d_in[10];
  const float* W_sub = (const float*)d_in[11];
  const float* b_sub = (const float*)d_in[12];
  const float* W_ins = (const float*)d_in[13];
  const float* b_ins = (const float*)d_in[14];
  float* out = (float*)d_out;

  char* w = (char*)d_ws;
  constexpr size_t FLAG_SZ = 512 * 32 * 4;                  // 64 KB, 128B-spread
  constexpr size_t TOK_SZ  = (size_t)SX_ * B_ * 4;
  constexpr size_t WCAT_SZ = (size_t)160 * 1024;            // head W fp8
  constexpr size_t W8F_SZ  = (size_t)2048 * 512;            // fwd Whh fp8
  constexpr size_t W8M_SZ  = (size_t)4096 * 1024;           // mod Whh fp8
  constexpr size_t EF_SZ   = (size_t)67 * 2048 * 4;         // E tables f32
  constexpr size_t EM_SZ   = (size_t)67 * 4096 * 4;
  constexpr size_t LX_SZ   = (size_t)SX_ * B_ * OP_ * 4;
  constexpr size_t HF_SZ   = (size_t)35 * B_ * 512;         // h slabs fp8
  constexpr size_t HM_SZ   = (size_t)35 * B_ * 1024;

  size_t off = 0;
  unsigned* flags = (unsigned*)(w + off); off += FLAG_SZ;
  int*  tok_x   = (int*)(w + off);  off += TOK_SZ;
  int*  tok_y   = (int*)(w + off);  off += TOK_SZ;
  off = (off + 255) & ~(size_t)255;
  u8*   Wcat    = (u8*)(w + off);   off += WCAT_SZ;
  u8*   w8_f    = (u8*)(w + off);   off += W8F_SZ;
  u8*   w8_r    = (u8*)(w + off);   off += W8F_SZ;
  u8*   w8_m    = (u8*)(w + off);   off += W8M_SZ;
  float* E_f    = (float*)(w + off); off += EF_SZ;
  float* E_r    = (float*)(w + off); off += EF_SZ;
  float* E_m    = (float*)(w + off); off += EM_SZ;
  float* lx_sub = (float*)(w + off); off += LX_SZ;
  float* lx_ins = (float*)(w + off); off += LX_SZ;
  float* ly_sub = (float*)(w + off); off += LX_SZ;
  float* ly_ins = (float*)(w + off); off += LX_SZ;
  u8* fwd_all   = (u8*)(w + off);   off += HF_SZ;
  u8* rev_all   = (u8*)(w + off);   off += HF_SZ;
  u8* y_all     = (u8*)(w + off);   off += HM_SZ;
  (void)ws_size; (void)in_sizes; (void)n_in; (void)out_size;

  (void)hipMemsetAsync(flags, 0, FLAG_SZ, stream);

  prep_all<<<3428, 256, 0, stream>>>(
      sources, targets, tok_x, tok_y,
      W_sub, W_ins, Wcat,
      Wih_f, b_f, Wih_r, b_r, Wih_m, b_m, E_f, E_r, E_m,
      Whh_f, Whh_r, Whh_m, w8_f, w8_r, w8_m);

  lstm_persist<<<512, 256, 0, stream>>>(
      tok_x, tok_y,
      E_f, w8_f,
      E_r, w8_r,
      E_m, w8_m,
      fwd_all, rev_all, y_all, flags);

  head_kernel<<<272, 256, 0, stream>>>(fwd_all, rev_all, y_all, Wcat,
                                       b_sub, b_ins, lx_sub, lx_ins, ly_sub, ly_ins);

  pair_kernel<<<272, 256, 0, stream>>>(tok_x, tok_y, lx_sub, lx_ins,
                                       ly_sub, ly_ins, out);
}